// Round 6
// baseline (113.489 us; speedup 1.0000x reference)
//
#include <hip/hip_runtime.h>
#include <cmath>

typedef unsigned int uint32;
typedef _Float16 v2h __attribute__((ext_vector_type(2)));
typedef _Float16 half8 __attribute__((ext_vector_type(8)));
typedef float v4f __attribute__((ext_vector_type(4)));

__device__ __forceinline__ float fast_tanh(float x) {
    float e = __expf(2.0f * x);
    return 1.0f - 2.0f * __builtin_amdgcn_rcpf(e + 1.0f);
}

__device__ __forceinline__ uint32 pkf(float x, float y) {
    v2h v; v.x = (_Float16)x; v.y = (_Float16)y;
    return __builtin_bit_cast(uint32, v);
}
__device__ __forceinline__ half8 h8(uint4 u) { return __builtin_bit_cast(half8, u); }

// One wave (64 lanes) integrates one batch row. One row per 64-thread block.
// R21 == R20 resubmitted verbatim (R20's bench was an infra failure:
// "MI355X container failed twice" — no pass/fail verdict, no counters).
// R20 changes:
//  - REVERT R19's 4-rows/block packing (regressed 41->49.5 us with identical
//    eval count & conflicts: co-scheduled lockstep waves of one workgroup
//    contend on SIMD issue; independent 64-thread blocks spread 1 wave/SIMD).
//  - NEW: both in-eval LDS exchanges (h1, h2) replaced by 16x ds_bpermute
//    each. Old path: ds_write -> fence -> 4x ds_read_b128 (store-to-load,
//    ~240 cy). New path: 16 independent register-dataflow bpermutes
//    (~60 cy latency + issue), no fences, no LDS arrays. Per-instruction
//    source pattern = 4 distinct banks + 16-way broadcast: conflict-free.
//  - Dense output kept parallel (R19-verified values): lanes 1..ri emit.
//  - Numerics IDENTICAL to R18 (verified): FSAL predictor-corrector
//    composite Simpson, 2 evals/8-unit window, static h=8 phase-1 loop
//    (same literals), tail Simpson h=r, boundary Y += f(len)/6.
// Critical path len=126: 33 evals.
__global__ __launch_bounds__(64, 1) void node_kernel(
    const float* __restrict__ y0,        // [B]
    const float* __restrict__ latent,    // [B,32]
    const int*   __restrict__ length,    // [B]
    const float* __restrict__ dense_cs,  // [B,D]
    const float* __restrict__ W1,        // [128,43]
    const float* __restrict__ b1,        // [128]
    const float* __restrict__ W2,        // [128,128]
    const float* __restrict__ b2,        // [128]
    const float* __restrict__ W3,        // [41,128]
    const float* __restrict__ b3,        // [41]
    float* __restrict__ out,             // [B,T]
    int T, int D)
{
    const int lane = threadIdx.x;        // 0..63
    const int row  = blockIdx.x;
    const int m16  = lane & 15;          // MFMA m/n index
    const int quad = lane >> 4;          // MFMA k-group
    const int u0 = lane * 2, u1 = u0 + 1;

    __shared__ __align__(16) float s_cq[256];   // c at half-integer times

    // ---- precompute concentration table (tau = q/2); single wave, DS
    //      ordering within a wave is in-order (no barrier needed) ----
    for (int q = lane; q < 256; q += 64) {
        const float tau = 0.5f * (float)q;
        int ii = (int)tau;
        int idx = ii + ((tau - (float)ii) > 0.0f ? 1 : 0);
        idx = min(max(idx, 1), D - 1);
        float w = tau - (float)(idx - 1);
        w = fminf(fmaxf(w, 0.0f), 1.0f);
        s_cq[q] = (1.0f - w) * dense_cs[row * D + idx - 1] + w * dense_cs[row * D + idx];
    }
    asm volatile("" ::: "memory");       // compiler-only ordering for s_cq

    // ---- W2 -> 32 A-fragments, pinned in AGPRs ----
    half8 w2f[8][4];
#pragma unroll
    for (int t = 0; t < 8; ++t) {
#pragma unroll
        for (int q = 0; q < 4; ++q) {
            const float* p = W2 + (16 * t + m16) * 128 + 32 * q + quad * 8;
            float4 f0 = *reinterpret_cast<const float4*>(p);
            float4 f1 = *reinterpret_cast<const float4*>(p + 4);
            uint4 u;
            u.x = pkf(f0.x, f0.y); u.y = pkf(f0.z, f0.w);
            u.z = pkf(f1.x, f1.y); u.w = pkf(f1.z, f1.w);
            w2f[t][q] = h8(u);
        }
    }
#pragma unroll
    for (int t = 0; t < 8; ++t)
#pragma unroll
        for (int q = 0; q < 4; ++q)
            asm volatile("" : "+a"(w2f[t][q]));   // AGPR-resident; MFMA reads in place

    // ---- W3 (padded to 16 rows) -> 4 A-fragments (AGPR); b3 -> C-fragment ----
    half8 w3f[4];
#pragma unroll
    for (int q = 0; q < 4; ++q) {
        uint4 u; float vals[8];
#pragma unroll
        for (int j = 0; j < 8; ++j) {
            const int k = 32 * q + quad * 8 + j;
            vals[j] = (m16 < 9) ? W3[m16 * 128 + k] : 0.0f;
        }
        u.x = pkf(vals[0], vals[1]); u.y = pkf(vals[2], vals[3]);
        u.z = pkf(vals[4], vals[5]); u.w = pkf(vals[6], vals[7]);
        w3f[q] = h8(u);
    }
#pragma unroll
    for (int q = 0; q < 4; ++q) asm volatile("" : "+a"(w3f[q]));

    v4f c3frag;
#pragma unroll
    for (int r = 0; r < 4; ++r) {
        const int i = quad * 4 + r;
        c3frag[r] = (i < 9) ? b3[i] : 0.0f;
    }

    // ---- W1 rows u0,u1 + layer-1 constants (VALU-side, VGPR) ----
    const float* W1r0 = W1 + u0 * 43;
    const float* W1r1 = W1 + u1 * 43;
    float w1a[11], w1b[11];
#pragma unroll
    for (int d = 0; d < 9; ++d) { w1a[d] = W1r0[d]; w1b[d] = W1r1[d]; }
    w1a[9] = W1r0[41]; w1a[10] = W1r0[42];
    w1b[9] = W1r1[41]; w1b[10] = W1r1[42];

    const float* lat = latent + row * 32;
    float c1a = b1[u0], c1b = b1[u1];
#pragma unroll
    for (int l = 0; l < 32; ++l) {
        float lv = lat[l];
        c1a = fmaf(W1r0[9 + l], lv, c1a);
        c1b = fmaf(W1r1[9 + l], lv, c1b);
    }
#pragma unroll
    for (int d = 0; d < 11; ++d) {
        asm volatile("" : "+v"(w1a[d]));
        asm volatile("" : "+v"(w1b[d]));
    }

    // ---- h2 pair ownership (from layer-2 C layout; R10/R11-verified) ----
    const int tsel = m16 >> 1;            // tile of owned values
    const int bsel = m16 & 1;             // reg pair: 0 -> {0,1}, 1 -> {2,3}
    const int i0 = 16 * tsel + 4 * quad + 2 * bsel;   // first owned unit
    const float b2v0 = b2[i0], b2v1 = b2[i0 + 1];

    // ---- bpermute source addresses (loop-invariant, live in VGPRs) ----
    // h1: pair position p is owned by lane p.  Need p = 16*qq + 4*quad + r.
    const int aq = quad << 4;             // byte addr of (4*quad)<<2
    // h2: pair position p = 8*(m16>>1) + 2*quad + (m16&1) owned by lane
    //     ((p>>1)&3)<<4 | ((p>>3)<<1) | (p&1).  Precompute the 16 readers.
    int adrB[16];
#pragma unroll
    for (int qq = 0; qq < 4; ++qq)
#pragma unroll
        for (int r = 0; r < 4; ++r) {
            const int p = 16 * qq + 4 * quad + r;
            const int owner = (((p >> 1) & 3) << 4) | (((p >> 3) << 1) | (p & 1));
            adrB[qq * 4 + r] = owner << 2;
        }

    // ---- integrator state, uniform in every lane ----
    const float y00 = y0[row];
    float Y[9], Ys[9];
#pragma unroll
    for (int i = 0; i < 9; ++i) { Y[i] = (i == 0) ? y00 : 0.0f; Ys[i] = Y[i]; }

    int len = length[row] - 1;           // length in [0,T) -> len in [0, T-2]
    if (len < 0) len = 0;
    const float tend = (float)len;
    if (lane == 0) out[row * T] = y00;

    const v4f zero4 = {0.0f, 0.0f, 0.0f, 0.0f};

    // One vector-field evaluation at (tau, c) on state Ys[] -> kk[0..8].
    // Arithmetic identical to R11-R19; exchanges now via ds_bpermute
    // (register dataflow, no LDS arrays, no fences).
    auto vf_eval = [&](float tau, float c, float* kk) __attribute__((always_inline)) {
        // ---- layer 1 (VALU): two accumulator chains ----
        float pa0 = c1a, pb0 = c1b, pa1 = 0.0f, pb1 = 0.0f;
#pragma unroll
        for (int d = 0; d < 4; ++d) {
            pa0 = fmaf(w1a[d], Ys[d], pa0);
            pb0 = fmaf(w1b[d], Ys[d], pb0);
        }
#pragma unroll
        for (int d = 4; d < 9; ++d) {
            pa1 = fmaf(w1a[d], Ys[d], pa1);
            pb1 = fmaf(w1b[d], Ys[d], pb1);
        }
        pa0 = fmaf(w1a[9], tau, pa0); pa1 = fmaf(w1a[10], c, pa1);
        pb0 = fmaf(w1b[9], tau, pb0); pb1 = fmaf(w1b[10], c, pb1);
        const int h1pair = (int)pkf(fast_tanh(pa0 + pa1), fast_tanh(pb0 + pb1));

        // ---- h1 -> B-fragments: 16 bpermutes (4 dwords per K-chunk) ----
        uint4 b1f[4];
#pragma unroll
        for (int qq = 0; qq < 4; ++qq) {
            const int base = aq + (qq << 6);
            b1f[qq].x = (uint32)__builtin_amdgcn_ds_bpermute(base,      h1pair);
            b1f[qq].y = (uint32)__builtin_amdgcn_ds_bpermute(base + 4,  h1pair);
            b1f[qq].z = (uint32)__builtin_amdgcn_ds_bpermute(base + 8,  h1pair);
            b1f[qq].w = (uint32)__builtin_amdgcn_ds_bpermute(base + 12, h1pair);
        }

        // ---- layer 2 on the matrix pipe: 8 tiles x 4 K-chunks ----
        v4f acc[8];
#pragma unroll
        for (int t = 0; t < 8; ++t) {
            v4f a = __builtin_amdgcn_mfma_f32_16x16x32_f16(w2f[t][0], h8(b1f[0]), zero4, 0, 0, 0);
            a = __builtin_amdgcn_mfma_f32_16x16x32_f16(w2f[t][1], h8(b1f[1]), a, 0, 0, 0);
            a = __builtin_amdgcn_mfma_f32_16x16x32_f16(w2f[t][2], h8(b1f[2]), a, 0, 0, 0);
            acc[t] = __builtin_amdgcn_mfma_f32_16x16x32_f16(w2f[t][3], h8(b1f[3]), a, 0, 0, 0);
        }

        // ---- owned-pair select tree (all columns identical) ----
        float e0[8], e1[8];
#pragma unroll
        for (int t = 0; t < 8; ++t) {
            e0[t] = bsel ? acc[t][2] : acc[t][0];
            e1[t] = bsel ? acc[t][3] : acc[t][1];
        }
        const bool s0b = (tsel & 1), s1b = (tsel & 2), s2b = (tsel & 4);
        float f00 = s0b ? e0[1] : e0[0], f01 = s0b ? e0[3] : e0[2];
        float f02 = s0b ? e0[5] : e0[4], f03 = s0b ? e0[7] : e0[6];
        float f10 = s0b ? e1[1] : e1[0], f11 = s0b ? e1[3] : e1[2];
        float f12 = s0b ? e1[5] : e1[4], f13 = s0b ? e1[7] : e1[6];
        float g00 = s1b ? f01 : f00, g01 = s1b ? f03 : f02;
        float g10 = s1b ? f11 : f10, g11 = s1b ? f13 : f12;
        const float v0 = s2b ? g01 : g00;
        const float v1 = s2b ? g11 : g10;

        // ---- h2 exchange: 16 bpermutes from precomputed owner lanes ----
        const int h2pair = (int)pkf(fast_tanh(v0 + b2v0), fast_tanh(v1 + b2v1));
        uint4 b2f[4];
#pragma unroll
        for (int qq = 0; qq < 4; ++qq) {
            b2f[qq].x = (uint32)__builtin_amdgcn_ds_bpermute(adrB[qq * 4 + 0], h2pair);
            b2f[qq].y = (uint32)__builtin_amdgcn_ds_bpermute(adrB[qq * 4 + 1], h2pair);
            b2f[qq].z = (uint32)__builtin_amdgcn_ds_bpermute(adrB[qq * 4 + 2], h2pair);
            b2f[qq].w = (uint32)__builtin_amdgcn_ds_bpermute(adrB[qq * 4 + 3], h2pair);
        }

        // ---- layer 3: 4 independent MFMAs + packed adds ----
        v4f m0 = __builtin_amdgcn_mfma_f32_16x16x32_f16(w3f[0], h8(b2f[0]), c3frag, 0, 0, 0);
        v4f m1 = __builtin_amdgcn_mfma_f32_16x16x32_f16(w3f[1], h8(b2f[1]), zero4, 0, 0, 0);
        v4f m2 = __builtin_amdgcn_mfma_f32_16x16x32_f16(w3f[2], h8(b2f[2]), zero4, 0, 0, 0);
        v4f m3 = __builtin_amdgcn_mfma_f32_16x16x32_f16(w3f[3], h8(b2f[3]), zero4, 0, 0, 0);
        v4f a3 = (m0 + m1) + (m2 + m3);

        // ---- broadcast the 9 outputs (row = quad*4+reg, col 0) ----
        float p[9];
#pragma unroll
        for (int i = 0; i < 9; ++i) {
            const int src = (i >> 2) * 16;
            int b = __builtin_amdgcn_readlane(
                        __builtin_bit_cast(int, a3[i & 3]), src);
            p[i] = __builtin_bit_cast(float, b);
        }

        // ---- vf finalize, uniform in every lane ----
        const float alive = (tau <= tend) ? 1.0f : 0.0f;
        kk[0] = alive * (-__cosf(p[0]));
#pragma unroll
        for (int i = 1; i < 9; ++i) kk[i] = alive * p[i];
    };

    // Parallel dense output (R19-verified values): lanes 1..ri-1 compute
    // their own interior Hermite point, lane ri stores the endpoint.
    auto emit_window = [&](float* obase, int ri, float hh,
                           float yA, float yM, float yE,
                           float s0, float sM, float sE)
        __attribute__((always_inline)) {
        if (lane >= 1 && lane <= ri) {
            if (lane == ri) {
                obase[ri] = yE;
            } else {
                const float invh = 1.0f / hh;
                const float tj = (float)lane;
                float th, base, Ac, Bc, Cc;
                if (tj <= hh) {
                    const float dyA = yM - yA;
                    th = tj * invh; base = yA;
                    Ac = hh * s0;
                    Bc = 3.0f * dyA - hh * (2.0f * s0 + sM);
                    Cc = -2.0f * dyA + hh * (s0 + sM);
                } else {
                    const float dyB = yE - yM;
                    th = (tj - hh) * invh; base = yM;
                    Ac = hh * sM;
                    Bc = 3.0f * dyB - hh * (2.0f * sM + sE);
                    Cc = -2.0f * dyB + hh * (sM + sE);
                }
                obase[lane] = fmaf(th, fmaf(th, fmaf(th, Cc, Bc), Ac), base);
            }
        }
    };

    float f0v[9], f4v[9], f8v[9];

    // ---- bootstrap: f0 = f(0, Y0) ----
    vf_eval(0.0f, s_cq[0], f0v);         // Ys == Y

    // ---- phase 1: composite-Simpson macro steps of 8 (static constants,
    //      literals identical to R18) ----
    const int n8 = len >> 3;
    for (int i = 0; i < n8; ++i) {
        const int q = 16 * i;                // 2*t0
        const float t0f = (float)(8 * i);
        // predict midnode (Euler-4)
#pragma unroll
        for (int d = 0; d < 9; ++d) Ys[d] = fmaf(4.0f, f0v[d], Y[d]);
        vf_eval(t0f + 4.0f, s_cq[q + 8], f4v);
        // predict endnode (midpoint-8 off f4)
#pragma unroll
        for (int d = 0; d < 9; ++d) Ys[d] = fmaf(8.0f, f4v[d], Y[d]);
        vf_eval(t0f + 8.0f, s_cq[q + 16], f8v);
        // correct: midpoint value (dim 0) + endpoint state (all dims)
        const float yA = Y[0];
        const float yM = Y[0] + (1.0f / 3.0f) * (5.0f * f0v[0] + 8.0f * f4v[0] - f8v[0]);
#pragma unroll
        for (int d = 0; d < 9; ++d)
            Y[d] = fmaf(4.0f / 3.0f, f0v[d] + 4.0f * f4v[d] + f8v[d], Y[d]);
        emit_window(out + row * T + 8 * i, 8, 4.0f,
                    yA, yM, Y[0], f0v[0], f4v[0], f8v[0]);
        // FSAL + reset eval state
#pragma unroll
        for (int d = 0; d < 9; ++d) { f0v[d] = f8v[d]; Ys[d] = Y[d]; }
    }

    // ---- tail: one Simpson step over [8*n8, len], r in 1..7; mid at
    //      half-integer (s_cq covers halves); end eval IS f(len) ----
    const int t0i = 8 * n8;
    const int r = len - t0i;             // 0..7
    if (r > 0) {
        const float hr = (float)r, hh = 0.5f * hr;
        const float t0f = (float)t0i;
#pragma unroll
        for (int d = 0; d < 9; ++d) Ys[d] = fmaf(hh, f0v[d], Y[d]);
        vf_eval(t0f + hh, s_cq[2 * t0i + r], f4v);
#pragma unroll
        for (int d = 0; d < 9; ++d) Ys[d] = fmaf(hr, f4v[d], Y[d]);
        vf_eval(t0f + hr, s_cq[2 * len], f8v);
        const float yA = Y[0];
        const float yM = fmaf(hh * (1.0f / 12.0f),
                              5.0f * f0v[0] + 8.0f * f4v[0] - f8v[0], Y[0]);
#pragma unroll
        for (int d = 0; d < 9; ++d)
            Y[d] = fmaf(hr * (1.0f / 6.0f), f0v[d] + 4.0f * f4v[d] + f8v[d], Y[d]);
        emit_window(out + row * T + t0i, r, hh,
                    yA, yM, Y[0], f0v[0], f4v[0], f8v[0]);
        // FSAL: f(len)
#pragma unroll
        for (int d = 0; d < 9; ++d) f0v[d] = f8v[d];
    }

    // ---- boundary step at t0 = len: Y += k1/6 with k1 = f(len) (FSAL) ----
    const float Yfin = fmaf(1.0f / 6.0f, f0v[0], Y[0]);
    if (lane == 0) out[row * T + len + 1] = Yfin;

    // ---- dead fill: everything after len+1 is frozen ----
    for (int i = len + 2 + lane; i < T; i += 64)
        out[row * T + i] = Yfin;
}

extern "C" void kernel_launch(void* const* d_in, const int* in_sizes, int n_in,
                              void* d_out, int out_size, void* d_ws, size_t ws_size,
                              hipStream_t stream) {
    // setup_inputs order:
    // 0 ts[T] 1 y0[B] 2 latent[B,32] 3 length[B] 4 dense_ts[D] 5 dense_cs[B,D]
    // 6 W1 7 b1 8 W2 9 b2 10 W3 11 b3
    const float* y0       = (const float*)d_in[1];
    const float* latent   = (const float*)d_in[2];
    const int*   length   = (const int*)  d_in[3];
    const float* dense_cs = (const float*)d_in[5];
    const float* W1 = (const float*)d_in[6];
    const float* b1 = (const float*)d_in[7];
    const float* W2 = (const float*)d_in[8];
    const float* b2 = (const float*)d_in[9];
    const float* W3 = (const float*)d_in[10];
    const float* b3 = (const float*)d_in[11];
    float* out = (float*)d_out;

    const int T = in_sizes[0];   // 128
    const int B = in_sizes[1];   // 1024
    const int D = in_sizes[4];   // 256

    node_kernel<<<B, 64, 0, stream>>>(y0, latent, length, dense_cs,
                                      W1, b1, W2, b2, W3, b3, out, T, D);
}

// Round 7
// 112.568 us; speedup vs baseline: 1.0082x; 1.0082x over previous
//
#include <hip/hip_runtime.h>
#include <cmath>

typedef unsigned int uint32;
typedef _Float16 v2h __attribute__((ext_vector_type(2)));
typedef _Float16 half8 __attribute__((ext_vector_type(8)));
typedef float v4f __attribute__((ext_vector_type(4)));

__device__ __forceinline__ float fast_tanh(float x) {
    float e = __expf(2.0f * x);
    return 1.0f - 2.0f * __builtin_amdgcn_rcpf(e + 1.0f);
}

__device__ __forceinline__ uint32 pkf(float x, float y) {
    v2h v; v.x = (_Float16)x; v.y = (_Float16)y;
    return __builtin_bit_cast(uint32, v);
}
__device__ __forceinline__ half8 h8(uint4 u) { return __builtin_bit_cast(half8, u); }

// One wave (64 lanes) integrates one batch row. One row per 64-thread block.
// R22 change: DUAL-EVAL INTERLEAVE. R21 fit: dur ~ 7us + 33 evals x ~1.05us;
// per-eval dependency chain (~2000cy) >> issue cost (~300 inst) -> the wave
// mostly WAITS. Fix: make each window's two evals INDEPENDENT by swapping
// the endnode predictor midpoint-8 (off f4) -> Euler-8 (off f0) — the exact
// predictor+weight (h*k1, weight h/6) that R17's SSPRK3 stage-2 used and the
// harness verified. Both node evals then depend only on f0 and are hand-
// interleaved phase-by-phase in one wave (vf_eval2): one stream's stalls
// hide under the other's issue. bpermute transport (R21) is the enabler:
// no memory-clobber fences to serialize the streams (R18's LDS path had
// asm ::: "memory" at each exchange).
//  - corrector, Simpson weights, spacing-4 c-sampling, dense output,
//    boundary step: byte-identical to R18/R21.
//  - tail: Euler-hh / Euler-hr predictors (hr<=7 < verified 8), dual-eval.
// Critical path len=126: 33 evals -> 1 + 16 interleaved windows.
__global__ __launch_bounds__(64, 1) void node_kernel(
    const float* __restrict__ y0,        // [B]
    const float* __restrict__ latent,    // [B,32]
    const int*   __restrict__ length,    // [B]
    const float* __restrict__ dense_cs,  // [B,D]
    const float* __restrict__ W1,        // [128,43]
    const float* __restrict__ b1,        // [128]
    const float* __restrict__ W2,        // [128,128]
    const float* __restrict__ b2,        // [128]
    const float* __restrict__ W3,        // [41,128]
    const float* __restrict__ b3,        // [41]
    float* __restrict__ out,             // [B,T]
    int T, int D)
{
    const int lane = threadIdx.x;        // 0..63
    const int row  = blockIdx.x;
    const int m16  = lane & 15;          // MFMA m/n index
    const int quad = lane >> 4;          // MFMA k-group
    const int u0 = lane * 2, u1 = u0 + 1;

    __shared__ __align__(16) float s_cq[256];   // c at half-integer times

    // ---- precompute concentration table (tau = q/2) ----
    for (int q = lane; q < 256; q += 64) {
        const float tau = 0.5f * (float)q;
        int ii = (int)tau;
        int idx = ii + ((tau - (float)ii) > 0.0f ? 1 : 0);
        idx = min(max(idx, 1), D - 1);
        float w = tau - (float)(idx - 1);
        w = fminf(fmaxf(w, 0.0f), 1.0f);
        s_cq[q] = (1.0f - w) * dense_cs[row * D + idx - 1] + w * dense_cs[row * D + idx];
    }
    asm volatile("" ::: "memory");       // compiler-only ordering for s_cq

    // ---- W2 -> 32 A-fragments, pinned in AGPRs ----
    half8 w2f[8][4];
#pragma unroll
    for (int t = 0; t < 8; ++t) {
#pragma unroll
        for (int q = 0; q < 4; ++q) {
            const float* p = W2 + (16 * t + m16) * 128 + 32 * q + quad * 8;
            float4 f0 = *reinterpret_cast<const float4*>(p);
            float4 f1 = *reinterpret_cast<const float4*>(p + 4);
            uint4 u;
            u.x = pkf(f0.x, f0.y); u.y = pkf(f0.z, f0.w);
            u.z = pkf(f1.x, f1.y); u.w = pkf(f1.z, f1.w);
            w2f[t][q] = h8(u);
        }
    }
#pragma unroll
    for (int t = 0; t < 8; ++t)
#pragma unroll
        for (int q = 0; q < 4; ++q)
            asm volatile("" : "+a"(w2f[t][q]));   // AGPR-resident; MFMA reads in place

    // ---- W3 (padded to 16 rows) -> 4 A-fragments (AGPR); b3 -> C-fragment ----
    half8 w3f[4];
#pragma unroll
    for (int q = 0; q < 4; ++q) {
        uint4 u; float vals[8];
#pragma unroll
        for (int j = 0; j < 8; ++j) {
            const int k = 32 * q + quad * 8 + j;
            vals[j] = (m16 < 9) ? W3[m16 * 128 + k] : 0.0f;
        }
        u.x = pkf(vals[0], vals[1]); u.y = pkf(vals[2], vals[3]);
        u.z = pkf(vals[4], vals[5]); u.w = pkf(vals[6], vals[7]);
        w3f[q] = h8(u);
    }
#pragma unroll
    for (int q = 0; q < 4; ++q) asm volatile("" : "+a"(w3f[q]));

    v4f c3frag;
#pragma unroll
    for (int r = 0; r < 4; ++r) {
        const int i = quad * 4 + r;
        c3frag[r] = (i < 9) ? b3[i] : 0.0f;
    }

    // ---- W1 rows u0,u1 + layer-1 constants (VALU-side, VGPR) ----
    const float* W1r0 = W1 + u0 * 43;
    const float* W1r1 = W1 + u1 * 43;
    float w1a[11], w1b[11];
#pragma unroll
    for (int d = 0; d < 9; ++d) { w1a[d] = W1r0[d]; w1b[d] = W1r1[d]; }
    w1a[9] = W1r0[41]; w1a[10] = W1r0[42];
    w1b[9] = W1r1[41]; w1b[10] = W1r1[42];

    const float* lat = latent + row * 32;
    float c1a = b1[u0], c1b = b1[u1];
#pragma unroll
    for (int l = 0; l < 32; ++l) {
        float lv = lat[l];
        c1a = fmaf(W1r0[9 + l], lv, c1a);
        c1b = fmaf(W1r1[9 + l], lv, c1b);
    }
#pragma unroll
    for (int d = 0; d < 11; ++d) {
        asm volatile("" : "+v"(w1a[d]));
        asm volatile("" : "+v"(w1b[d]));
    }

    // ---- h2 pair ownership (from layer-2 C layout; R10/R11-verified) ----
    const int tsel = m16 >> 1;            // tile of owned values
    const int bsel = m16 & 1;             // reg pair: 0 -> {0,1}, 1 -> {2,3}
    const int i0 = 16 * tsel + 4 * quad + 2 * bsel;   // first owned unit
    const float b2v0 = b2[i0], b2v1 = b2[i0 + 1];

    // ---- bpermute source addresses (loop-invariant, live in VGPRs) ----
    const int aq = quad << 4;             // h1: owner lane == pair position
    int adrB[16];                         // h2: closed-form owner inversion
#pragma unroll
    for (int qq = 0; qq < 4; ++qq)
#pragma unroll
        for (int r = 0; r < 4; ++r) {
            const int p = 16 * qq + 4 * quad + r;
            const int owner = (((p >> 1) & 3) << 4) | (((p >> 3) << 1) | (p & 1));
            adrB[qq * 4 + r] = owner << 2;
        }

    // ---- integrator state, uniform in every lane ----
    const float y00 = y0[row];
    float Y[9], Ys[9], Ysb[9];
#pragma unroll
    for (int i = 0; i < 9; ++i) { Y[i] = (i == 0) ? y00 : 0.0f; Ys[i] = Y[i]; Ysb[i] = Y[i]; }

    int len = length[row] - 1;           // length in [0,T) -> len in [0, T-2]
    if (len < 0) len = 0;
    const float tend = (float)len;
    if (lane == 0) out[row * T] = y00;

    const v4f zero4 = {0.0f, 0.0f, 0.0f, 0.0f};

    // Single vector-field evaluation (bootstrap only); identical machinery.
    auto vf_eval = [&](float tau, float c, float* kk) __attribute__((always_inline)) {
        float pa0 = c1a, pb0 = c1b, pa1 = 0.0f, pb1 = 0.0f;
#pragma unroll
        for (int d = 0; d < 4; ++d) {
            pa0 = fmaf(w1a[d], Ys[d], pa0);
            pb0 = fmaf(w1b[d], Ys[d], pb0);
        }
#pragma unroll
        for (int d = 4; d < 9; ++d) {
            pa1 = fmaf(w1a[d], Ys[d], pa1);
            pb1 = fmaf(w1b[d], Ys[d], pb1);
        }
        pa0 = fmaf(w1a[9], tau, pa0); pa1 = fmaf(w1a[10], c, pa1);
        pb0 = fmaf(w1b[9], tau, pb0); pb1 = fmaf(w1b[10], c, pb1);
        const int h1pair = (int)pkf(fast_tanh(pa0 + pa1), fast_tanh(pb0 + pb1));

        uint4 b1f[4];
#pragma unroll
        for (int qq = 0; qq < 4; ++qq) {
            const int base = aq + (qq << 6);
            b1f[qq].x = (uint32)__builtin_amdgcn_ds_bpermute(base,      h1pair);
            b1f[qq].y = (uint32)__builtin_amdgcn_ds_bpermute(base + 4,  h1pair);
            b1f[qq].z = (uint32)__builtin_amdgcn_ds_bpermute(base + 8,  h1pair);
            b1f[qq].w = (uint32)__builtin_amdgcn_ds_bpermute(base + 12, h1pair);
        }

        v4f acc[8];
#pragma unroll
        for (int t = 0; t < 8; ++t) {
            v4f a = __builtin_amdgcn_mfma_f32_16x16x32_f16(w2f[t][0], h8(b1f[0]), zero4, 0, 0, 0);
            a = __builtin_amdgcn_mfma_f32_16x16x32_f16(w2f[t][1], h8(b1f[1]), a, 0, 0, 0);
            a = __builtin_amdgcn_mfma_f32_16x16x32_f16(w2f[t][2], h8(b1f[2]), a, 0, 0, 0);
            acc[t] = __builtin_amdgcn_mfma_f32_16x16x32_f16(w2f[t][3], h8(b1f[3]), a, 0, 0, 0);
        }

        float e0[8], e1[8];
#pragma unroll
        for (int t = 0; t < 8; ++t) {
            e0[t] = bsel ? acc[t][2] : acc[t][0];
            e1[t] = bsel ? acc[t][3] : acc[t][1];
        }
        const bool s0b = (tsel & 1), s1b = (tsel & 2), s2b = (tsel & 4);
        float f00 = s0b ? e0[1] : e0[0], f01 = s0b ? e0[3] : e0[2];
        float f02 = s0b ? e0[5] : e0[4], f03 = s0b ? e0[7] : e0[6];
        float f10 = s0b ? e1[1] : e1[0], f11 = s0b ? e1[3] : e1[2];
        float f12 = s0b ? e1[5] : e1[4], f13 = s0b ? e1[7] : e1[6];
        float g00 = s1b ? f01 : f00, g01 = s1b ? f03 : f02;
        float g10 = s1b ? f11 : f10, g11 = s1b ? f13 : f12;
        const float v0 = s2b ? g01 : g00;
        const float v1 = s2b ? g11 : g10;

        const int h2pair = (int)pkf(fast_tanh(v0 + b2v0), fast_tanh(v1 + b2v1));
        uint4 b2f[4];
#pragma unroll
        for (int qq = 0; qq < 4; ++qq) {
            b2f[qq].x = (uint32)__builtin_amdgcn_ds_bpermute(adrB[qq * 4 + 0], h2pair);
            b2f[qq].y = (uint32)__builtin_amdgcn_ds_bpermute(adrB[qq * 4 + 1], h2pair);
            b2f[qq].z = (uint32)__builtin_amdgcn_ds_bpermute(adrB[qq * 4 + 2], h2pair);
            b2f[qq].w = (uint32)__builtin_amdgcn_ds_bpermute(adrB[qq * 4 + 3], h2pair);
        }

        v4f m0 = __builtin_amdgcn_mfma_f32_16x16x32_f16(w3f[0], h8(b2f[0]), c3frag, 0, 0, 0);
        v4f m1 = __builtin_amdgcn_mfma_f32_16x16x32_f16(w3f[1], h8(b2f[1]), zero4, 0, 0, 0);
        v4f m2 = __builtin_amdgcn_mfma_f32_16x16x32_f16(w3f[2], h8(b2f[2]), zero4, 0, 0, 0);
        v4f m3 = __builtin_amdgcn_mfma_f32_16x16x32_f16(w3f[3], h8(b2f[3]), zero4, 0, 0, 0);
        v4f a3 = (m0 + m1) + (m2 + m3);

        float p[9];
#pragma unroll
        for (int i = 0; i < 9; ++i) {
            const int src = (i >> 2) * 16;
            int b = __builtin_amdgcn_readlane(
                        __builtin_bit_cast(int, a3[i & 3]), src);
            p[i] = __builtin_bit_cast(float, b);
        }

        const float alive = (tau <= tend) ? 1.0f : 0.0f;
        kk[0] = alive * (-__cosf(p[0]));
#pragma unroll
        for (int i = 1; i < 9; ++i) kk[i] = alive * p[i];
    };

    // DUAL vector-field evaluation: two independent states (Ys, Ysb),
    // streams hand-interleaved phase-by-phase so one stream's latency
    // hides under the other's issue. Arithmetic per stream identical to
    // vf_eval.
    auto vf_eval2 = [&](float tauA, float cA, float tauB, float cB,
                        float* kkA, float* kkB) __attribute__((always_inline)) {
        // ---- layer 1, both streams ----
        float Apa0 = c1a, Apb0 = c1b, Apa1 = 0.0f, Apb1 = 0.0f;
        float Bpa0 = c1a, Bpb0 = c1b, Bpa1 = 0.0f, Bpb1 = 0.0f;
#pragma unroll
        for (int d = 0; d < 4; ++d) {
            Apa0 = fmaf(w1a[d], Ys[d],  Apa0);  Apb0 = fmaf(w1b[d], Ys[d],  Apb0);
            Bpa0 = fmaf(w1a[d], Ysb[d], Bpa0);  Bpb0 = fmaf(w1b[d], Ysb[d], Bpb0);
        }
#pragma unroll
        for (int d = 4; d < 9; ++d) {
            Apa1 = fmaf(w1a[d], Ys[d],  Apa1);  Apb1 = fmaf(w1b[d], Ys[d],  Apb1);
            Bpa1 = fmaf(w1a[d], Ysb[d], Bpa1);  Bpb1 = fmaf(w1b[d], Ysb[d], Bpb1);
        }
        Apa0 = fmaf(w1a[9], tauA, Apa0); Apa1 = fmaf(w1a[10], cA, Apa1);
        Apb0 = fmaf(w1b[9], tauA, Apb0); Apb1 = fmaf(w1b[10], cA, Apb1);
        Bpa0 = fmaf(w1a[9], tauB, Bpa0); Bpa1 = fmaf(w1a[10], cB, Bpa1);
        Bpb0 = fmaf(w1b[9], tauB, Bpb0); Bpb1 = fmaf(w1b[10], cB, Bpb1);
        const int h1A = (int)pkf(fast_tanh(Apa0 + Apa1), fast_tanh(Apb0 + Apb1));
        const int h1B = (int)pkf(fast_tanh(Bpa0 + Bpa1), fast_tanh(Bpb0 + Bpb1));

        // ---- h1 exchange, both streams (32 bpermutes) ----
        uint4 b1fA[4], b1fB[4];
#pragma unroll
        for (int qq = 0; qq < 4; ++qq) {
            const int base = aq + (qq << 6);
            b1fA[qq].x = (uint32)__builtin_amdgcn_ds_bpermute(base,      h1A);
            b1fB[qq].x = (uint32)__builtin_amdgcn_ds_bpermute(base,      h1B);
            b1fA[qq].y = (uint32)__builtin_amdgcn_ds_bpermute(base + 4,  h1A);
            b1fB[qq].y = (uint32)__builtin_amdgcn_ds_bpermute(base + 4,  h1B);
            b1fA[qq].z = (uint32)__builtin_amdgcn_ds_bpermute(base + 8,  h1A);
            b1fB[qq].z = (uint32)__builtin_amdgcn_ds_bpermute(base + 8,  h1B);
            b1fA[qq].w = (uint32)__builtin_amdgcn_ds_bpermute(base + 12, h1A);
            b1fB[qq].w = (uint32)__builtin_amdgcn_ds_bpermute(base + 12, h1B);
        }

        // ---- layer 2, A/B alternated per MFMA (independent chains) ----
        v4f accA[8], accB[8];
#pragma unroll
        for (int t = 0; t < 8; ++t) {
            v4f a = __builtin_amdgcn_mfma_f32_16x16x32_f16(w2f[t][0], h8(b1fA[0]), zero4, 0, 0, 0);
            v4f b = __builtin_amdgcn_mfma_f32_16x16x32_f16(w2f[t][0], h8(b1fB[0]), zero4, 0, 0, 0);
            a = __builtin_amdgcn_mfma_f32_16x16x32_f16(w2f[t][1], h8(b1fA[1]), a, 0, 0, 0);
            b = __builtin_amdgcn_mfma_f32_16x16x32_f16(w2f[t][1], h8(b1fB[1]), b, 0, 0, 0);
            a = __builtin_amdgcn_mfma_f32_16x16x32_f16(w2f[t][2], h8(b1fA[2]), a, 0, 0, 0);
            b = __builtin_amdgcn_mfma_f32_16x16x32_f16(w2f[t][2], h8(b1fB[2]), b, 0, 0, 0);
            accA[t] = __builtin_amdgcn_mfma_f32_16x16x32_f16(w2f[t][3], h8(b1fA[3]), a, 0, 0, 0);
            accB[t] = __builtin_amdgcn_mfma_f32_16x16x32_f16(w2f[t][3], h8(b1fB[3]), b, 0, 0, 0);
        }

        // ---- select trees, both streams ----
        const bool s0b = (tsel & 1), s1b = (tsel & 2), s2b = (tsel & 4);
        float v0A, v1A, v0B, v1B;
        {
            float e0[8], e1[8];
#pragma unroll
            for (int t = 0; t < 8; ++t) {
                e0[t] = bsel ? accA[t][2] : accA[t][0];
                e1[t] = bsel ? accA[t][3] : accA[t][1];
            }
            float f00 = s0b ? e0[1] : e0[0], f01 = s0b ? e0[3] : e0[2];
            float f02 = s0b ? e0[5] : e0[4], f03 = s0b ? e0[7] : e0[6];
            float f10 = s0b ? e1[1] : e1[0], f11 = s0b ? e1[3] : e1[2];
            float f12 = s0b ? e1[5] : e1[4], f13 = s0b ? e1[7] : e1[6];
            float g00 = s1b ? f01 : f00, g01 = s1b ? f03 : f02;
            float g10 = s1b ? f11 : f10, g11 = s1b ? f13 : f12;
            v0A = s2b ? g01 : g00; v1A = s2b ? g11 : g10;
        }
        {
            float e0[8], e1[8];
#pragma unroll
            for (int t = 0; t < 8; ++t) {
                e0[t] = bsel ? accB[t][2] : accB[t][0];
                e1[t] = bsel ? accB[t][3] : accB[t][1];
            }
            float f00 = s0b ? e0[1] : e0[0], f01 = s0b ? e0[3] : e0[2];
            float f02 = s0b ? e0[5] : e0[4], f03 = s0b ? e0[7] : e0[6];
            float f10 = s0b ? e1[1] : e1[0], f11 = s0b ? e1[3] : e1[2];
            float f12 = s0b ? e1[5] : e1[4], f13 = s0b ? e1[7] : e1[6];
            float g00 = s1b ? f01 : f00, g01 = s1b ? f03 : f02;
            float g10 = s1b ? f11 : f10, g11 = s1b ? f13 : f12;
            v0B = s2b ? g01 : g00; v1B = s2b ? g11 : g10;
        }

        // ---- h2 exchange, both streams (32 bpermutes) ----
        const int h2A = (int)pkf(fast_tanh(v0A + b2v0), fast_tanh(v1A + b2v1));
        const int h2B = (int)pkf(fast_tanh(v0B + b2v0), fast_tanh(v1B + b2v1));
        uint4 b2fA[4], b2fB[4];
#pragma unroll
        for (int qq = 0; qq < 4; ++qq) {
            b2fA[qq].x = (uint32)__builtin_amdgcn_ds_bpermute(adrB[qq * 4 + 0], h2A);
            b2fB[qq].x = (uint32)__builtin_amdgcn_ds_bpermute(adrB[qq * 4 + 0], h2B);
            b2fA[qq].y = (uint32)__builtin_amdgcn_ds_bpermute(adrB[qq * 4 + 1], h2A);
            b2fB[qq].y = (uint32)__builtin_amdgcn_ds_bpermute(adrB[qq * 4 + 1], h2B);
            b2fA[qq].z = (uint32)__builtin_amdgcn_ds_bpermute(adrB[qq * 4 + 2], h2A);
            b2fB[qq].z = (uint32)__builtin_amdgcn_ds_bpermute(adrB[qq * 4 + 2], h2B);
            b2fA[qq].w = (uint32)__builtin_amdgcn_ds_bpermute(adrB[qq * 4 + 3], h2A);
            b2fB[qq].w = (uint32)__builtin_amdgcn_ds_bpermute(adrB[qq * 4 + 3], h2B);
        }

        // ---- layer 3, alternated ----
        v4f m0A = __builtin_amdgcn_mfma_f32_16x16x32_f16(w3f[0], h8(b2fA[0]), c3frag, 0, 0, 0);
        v4f m0B = __builtin_amdgcn_mfma_f32_16x16x32_f16(w3f[0], h8(b2fB[0]), c3frag, 0, 0, 0);
        v4f m1A = __builtin_amdgcn_mfma_f32_16x16x32_f16(w3f[1], h8(b2fA[1]), zero4, 0, 0, 0);
        v4f m1B = __builtin_amdgcn_mfma_f32_16x16x32_f16(w3f[1], h8(b2fB[1]), zero4, 0, 0, 0);
        v4f m2A = __builtin_amdgcn_mfma_f32_16x16x32_f16(w3f[2], h8(b2fA[2]), zero4, 0, 0, 0);
        v4f m2B = __builtin_amdgcn_mfma_f32_16x16x32_f16(w3f[2], h8(b2fB[2]), zero4, 0, 0, 0);
        v4f m3A = __builtin_amdgcn_mfma_f32_16x16x32_f16(w3f[3], h8(b2fA[3]), zero4, 0, 0, 0);
        v4f m3B = __builtin_amdgcn_mfma_f32_16x16x32_f16(w3f[3], h8(b2fB[3]), zero4, 0, 0, 0);
        v4f a3A = (m0A + m1A) + (m2A + m3A);
        v4f a3B = (m0B + m1B) + (m2B + m3B);

        // ---- broadcast the 9 outputs, both streams ----
        float pA[9], pB[9];
#pragma unroll
        for (int i = 0; i < 9; ++i) {
            const int src = (i >> 2) * 16;
            int ba = __builtin_amdgcn_readlane(__builtin_bit_cast(int, a3A[i & 3]), src);
            int bb = __builtin_amdgcn_readlane(__builtin_bit_cast(int, a3B[i & 3]), src);
            pA[i] = __builtin_bit_cast(float, ba);
            pB[i] = __builtin_bit_cast(float, bb);
        }

        // ---- finalize, both streams ----
        const float aliveA = (tauA <= tend) ? 1.0f : 0.0f;
        const float aliveB = (tauB <= tend) ? 1.0f : 0.0f;
        kkA[0] = aliveA * (-__cosf(pA[0]));
        kkB[0] = aliveB * (-__cosf(pB[0]));
#pragma unroll
        for (int i = 1; i < 9; ++i) {
            kkA[i] = aliveA * pA[i];
            kkB[i] = aliveB * pB[i];
        }
    };

    // Parallel dense output (R19/R21-verified values).
    auto emit_window = [&](float* obase, int ri, float hh,
                           float yA, float yM, float yE,
                           float s0, float sM, float sE)
        __attribute__((always_inline)) {
        if (lane >= 1 && lane <= ri) {
            if (lane == ri) {
                obase[ri] = yE;
            } else {
                const float invh = 1.0f / hh;
                const float tj = (float)lane;
                float th, base, Ac, Bc, Cc;
                if (tj <= hh) {
                    const float dyA = yM - yA;
                    th = tj * invh; base = yA;
                    Ac = hh * s0;
                    Bc = 3.0f * dyA - hh * (2.0f * s0 + sM);
                    Cc = -2.0f * dyA + hh * (s0 + sM);
                } else {
                    const float dyB = yE - yM;
                    th = (tj - hh) * invh; base = yM;
                    Ac = hh * sM;
                    Bc = 3.0f * dyB - hh * (2.0f * sM + sE);
                    Cc = -2.0f * dyB + hh * (sM + sE);
                }
                obase[lane] = fmaf(th, fmaf(th, fmaf(th, Cc, Bc), Ac), base);
            }
        }
    };

    float f0v[9], f4v[9], f8v[9];

    // ---- bootstrap: f0 = f(0, Y0) ----
    vf_eval(0.0f, s_cq[0], f0v);         // Ys == Y

    // ---- phase 1: windows of 8; mid+end evals INDEPENDENT (Euler-4 /
    //      Euler-8 predictors off f0) and co-scheduled via vf_eval2 ----
    const int n8 = len >> 3;
    for (int i = 0; i < n8; ++i) {
        const int q = 16 * i;                // 2*t0
        const float t0f = (float)(8 * i);
#pragma unroll
        for (int d = 0; d < 9; ++d) {
            Ys[d]  = fmaf(4.0f, f0v[d], Y[d]);   // midnode: Euler-4 (R18-verified)
            Ysb[d] = fmaf(8.0f, f0v[d], Y[d]);   // endnode: Euler-8 (R17-verified)
        }
        vf_eval2(t0f + 4.0f, s_cq[q + 8], t0f + 8.0f, s_cq[q + 16], f4v, f8v);
        // correct: midpoint value (dim 0) + endpoint state (all dims)
        const float yA = Y[0];
        const float yM = Y[0] + (1.0f / 3.0f) * (5.0f * f0v[0] + 8.0f * f4v[0] - f8v[0]);
#pragma unroll
        for (int d = 0; d < 9; ++d)
            Y[d] = fmaf(4.0f / 3.0f, f0v[d] + 4.0f * f4v[d] + f8v[d], Y[d]);
        emit_window(out + row * T + 8 * i, 8, 4.0f,
                    yA, yM, Y[0], f0v[0], f4v[0], f8v[0]);
        // FSAL
#pragma unroll
        for (int d = 0; d < 9; ++d) f0v[d] = f8v[d];
    }

    // ---- tail: one Simpson step over [8*n8, len], r in 1..7; Euler-hh /
    //      Euler-hr predictors (both < verified 8), dual-eval ----
    const int t0i = 8 * n8;
    const int r = len - t0i;             // 0..7
    if (r > 0) {
        const float hr = (float)r, hh = 0.5f * hr;
        const float t0f = (float)t0i;
#pragma unroll
        for (int d = 0; d < 9; ++d) {
            Ys[d]  = fmaf(hh, f0v[d], Y[d]);
            Ysb[d] = fmaf(hr, f0v[d], Y[d]);
        }
        vf_eval2(t0f + hh, s_cq[2 * t0i + r], t0f + hr, s_cq[2 * len], f4v, f8v);
        const float yA = Y[0];
        const float yM = fmaf(hh * (1.0f / 12.0f),
                              5.0f * f0v[0] + 8.0f * f4v[0] - f8v[0], Y[0]);
#pragma unroll
        for (int d = 0; d < 9; ++d)
            Y[d] = fmaf(hr * (1.0f / 6.0f), f0v[d] + 4.0f * f4v[d] + f8v[d], Y[d]);
        emit_window(out + row * T + t0i, r, hh,
                    yA, yM, Y[0], f0v[0], f4v[0], f8v[0]);
#pragma unroll
        for (int d = 0; d < 9; ++d) f0v[d] = f8v[d];
    }

    // ---- boundary step at t0 = len: Y += k1/6 with k1 = f(len) (FSAL) ----
    const float Yfin = fmaf(1.0f / 6.0f, f0v[0], Y[0]);
    if (lane == 0) out[row * T + len + 1] = Yfin;

    // ---- dead fill: everything after len+1 is frozen ----
    for (int i = len + 2 + lane; i < T; i += 64)
        out[row * T + i] = Yfin;
}

extern "C" void kernel_launch(void* const* d_in, const int* in_sizes, int n_in,
                              void* d_out, int out_size, void* d_ws, size_t ws_size,
                              hipStream_t stream) {
    // setup_inputs order:
    // 0 ts[T] 1 y0[B] 2 latent[B,32] 3 length[B] 4 dense_ts[D] 5 dense_cs[B,D]
    // 6 W1 7 b1 8 W2 9 b2 10 W3 11 b3
    const float* y0       = (const float*)d_in[1];
    const float* latent   = (const float*)d_in[2];
    const int*   length   = (const int*)  d_in[3];
    const float* dense_cs = (const float*)d_in[5];
    const float* W1 = (const float*)d_in[6];
    const float* b1 = (const float*)d_in[7];
    const float* W2 = (const float*)d_in[8];
    const float* b2 = (const float*)d_in[9];
    const float* W3 = (const float*)d_in[10];
    const float* b3 = (const float*)d_in[11];
    float* out = (float*)d_out;

    const int T = in_sizes[0];   // 128
    const int B = in_sizes[1];   // 1024
    const int D = in_sizes[4];   // 256

    node_kernel<<<B, 64, 0, stream>>>(y0, latent, length, dense_cs,
                                      W1, b1, W2, b2, W3, b3, out, T, D);
}